// Round 14
// baseline (404.245 us; speedup 1.0000x reference)
//
#include <hip/hip_runtime.h>
#include <hip/hip_bf16.h>

#define NODES 50000
#define EDGES 800000
#define BSH 8
#define NBUCK 196          // ceil(50000 / 256)
#define NBIN_BLOCKS 391    // ceil(800000 / 2048)
#define NGRP 6250          // NODES / 8
#define GPB 4              // node-groups per block (grid-stride)
#define LGRID 1563         // ceil(NGRP / GPB)

__device__ __forceinline__ float elu1(float x) { return x > 0.f ? x : expm1f(x); }

union F4 { float4 v; float f[4]; };

// ---------------- bucket histogram (256-node buckets) ----------------
__global__ __launch_bounds__(256) void k_bhist(const int* __restrict__ ei, int* __restrict__ bucket_cnt) {
  __shared__ int cnt[NBUCK];
  int t = threadIdx.x;
  for (int i = t; i < NBUCK; i += 256) cnt[i] = 0;
  __syncthreads();
  int base = blockIdx.x * 2048;
#pragma unroll
  for (int i = 0; i < 8; i++) {
    int e = base + i * 256 + t;
    if (e < EDGES) atomicAdd(&cnt[ei[e * 3 + 1] >> BSH], 1);
  }
  __syncthreads();
  for (int i = t; i < NBUCK; i += 256)
    if (cnt[i]) atomicAdd(bucket_cnt + i, cnt[i]);
}

__global__ __launch_bounds__(256) void k_bscan(const int* __restrict__ bucket_cnt,
                                               int* __restrict__ bucket_base,
                                               int* __restrict__ bucket_cursor) {
  __shared__ int s[256];
  int t = threadIdx.x;
  int v = (t < NBUCK) ? bucket_cnt[t] : 0;
  s[t] = v;
  __syncthreads();
  for (int o = 1; o < 256; o <<= 1) {
    int x = (t >= o) ? s[t - o] : 0;
    __syncthreads();
    s[t] += x;
    __syncthreads();
  }
  if (t < NBUCK) { int e = s[t] - v; bucket_base[t] = e; bucket_cursor[t] = e; }
}

// pass A: bin edges by tgt-bucket; packed record: src[15:0] | sign[16] | tgtlow8[24:17]
__global__ __launch_bounds__(256) void k_bin(const int* __restrict__ ei,
                                             int* __restrict__ bucket_cursor,
                                             unsigned* __restrict__ binned) {
  __shared__ int cnt[NBUCK], basec[NBUCK];
  int t = threadIdx.x;
  for (int i = t; i < NBUCK; i += 256) cnt[i] = 0;
  __syncthreads();
  int eb = blockIdx.x * 2048;
#pragma unroll
  for (int i = 0; i < 8; i++) {
    int e = eb + i * 256 + t;
    if (e < EDGES) atomicAdd(&cnt[ei[e * 3 + 1] >> BSH], 1);
  }
  __syncthreads();
  for (int i = t; i < NBUCK; i += 256) {
    int c = cnt[i];
    basec[i] = c ? atomicAdd(bucket_cursor + i, c) : 0;
    cnt[i] = 0;
  }
  __syncthreads();
#pragma unroll
  for (int i = 0; i < 8; i++) {
    int e = eb + i * 256 + t;
    if (e < EDGES) {
      int src = ei[e * 3 + 0];
      int tgt = ei[e * 3 + 1];
      int sg  = ei[e * 3 + 2];
      unsigned val = (unsigned)src | (sg < 0 ? 0x10000u : 0u) | ((unsigned)(tgt & 255) << 17);
      int bkt = tgt >> BSH;
      int r = atomicAdd(&cnt[bkt], 1);
      binned[basec[bkt] + r] = val;
    }
  }
}

// pass B: derives offs from per-bucket histogram+scan, then scatters.
// perm entry = BYTE offset into interleaved ypn table: src*128 + sign*64.
__global__ __launch_bounds__(256) void k_scatter2(const unsigned* __restrict__ binned,
                                                  const int* __restrict__ bucket_base,
                                                  const int* __restrict__ bucket_cnt,
                                                  int* __restrict__ offs,
                                                  unsigned* __restrict__ perm) {
  __shared__ int cnt[256];
  __shared__ int s[256];
  int b = blockIdx.x, t = threadIdx.x;
  int t0 = b << BSH;
  cnt[t] = 0;
  __syncthreads();
  int n = bucket_cnt[b], bb = bucket_base[b];
  for (int i = t; i < n; i += 256) atomicAdd(&cnt[(binned[bb + i] >> 17) & 255], 1);
  __syncthreads();
  int v = cnt[t];
  s[t] = v;
  __syncthreads();
  for (int o = 1; o < 256; o <<= 1) {
    int x = (t >= o) ? s[t - o] : 0;
    __syncthreads();
    s[t] += x;
    __syncthreads();
  }
  int pos = bb + s[t] - v;
  if (t0 + t < NODES) offs[t0 + t] = pos;
  cnt[t] = pos;
  if (b == 0 && t == 0) offs[NODES] = EDGES;
  __syncthreads();
  for (int i = t; i < n; i += 256) {
    unsigned e = binned[bb + i];
    int p = atomicAdd(&cnt[(e >> 17) & 255], 1);
    perm[p] = ((e & 0xFFFFu) << 7) | ((e & 0x10000u) >> 10);  // src*128 + sign*64
  }
}

// ---------------- first linear: y = x @ {Wp,Wn,Ws}.T (out 32, K=64) -> interleaved ypn + ysb ----------------
__global__ __launch_bounds__(256) void k_lin64(const float* __restrict__ x,
    const float* __restrict__ Wp, const float* __restrict__ Wn, const float* __restrict__ Ws,
    unsigned short* __restrict__ ypn, unsigned short* __restrict__ ysb) {
  constexpr int K4 = 16;
  __shared__ float4 wp[K4][32], wn[K4][32], wsm[K4][32];
  __shared__ float4 xs[8][K4];
  for (int i = threadIdx.x; i < 32 * K4; i += 256) {
    int k4 = i >> 5, c = i & 31;
    wp[k4][c]  = ((const float4*)Wp)[c * K4 + k4];
    wn[k4][c]  = ((const float4*)Wn)[c * K4 + k4];
    wsm[k4][c] = ((const float4*)Ws)[c * K4 + k4];
  }
  int base = blockIdx.x * 8;
  for (int i = threadIdx.x; i < 8 * K4; i += 256) {
    int r = i / K4, k4 = i - r * K4;
    xs[r][k4] = ((const float4*)(x + (size_t)(base + r) * 64))[k4];
  }
  __syncthreads();
  int lane = threadIdx.x & 31, local = threadIdx.x >> 5;
  float ap = 0.f, an = 0.f, asf = 0.f;
#pragma unroll
  for (int k4 = 0; k4 < K4; k4++) {
    float4 xv = xs[local][k4];
    float4 a = wp[k4][lane], b = wn[k4][lane], c = wsm[k4][lane];
    ap  = fmaf(xv.w, a.w, fmaf(xv.z, a.z, fmaf(xv.y, a.y, fmaf(xv.x, a.x, ap))));
    an  = fmaf(xv.w, b.w, fmaf(xv.z, b.z, fmaf(xv.y, b.y, fmaf(xv.x, b.x, an))));
    asf = fmaf(xv.w, c.w, fmaf(xv.z, c.z, fmaf(xv.y, c.y, fmaf(xv.x, c.x, asf))));
  }
  int node = base + local;
  size_t o64 = (size_t)node * 64 + lane;
  ypn[o64]      = __bfloat16_as_ushort(__float2bfloat16(ap));
  ypn[o64 + 32] = __bfloat16_as_ushort(__float2bfloat16(an));
  ysb[(size_t)node * 32 + lane] = __bfloat16_as_ushort(__float2bfloat16(asf));
}

#define ACC8(A, V)                                   \
  A[0] += __uint_as_float((V).x << 16);              \
  A[1] += __uint_as_float((V).x & 0xffff0000u);      \
  A[2] += __uint_as_float((V).y << 16);              \
  A[3] += __uint_as_float((V).y & 0xffff0000u);      \
  A[4] += __uint_as_float((V).z << 16);              \
  A[5] += __uint_as_float((V).z & 0xffff0000u);      \
  A[6] += __uint_as_float((V).w << 16);              \
  A[7] += __uint_as_float((V).w & 0xffff0000u);

// ---------------- fused layer: gather + ELU (+res) (+ASFR) (+lin) ----------------
// Grid-stride (GPB groups/block): longer block lifetime, weights staged once.
// Interleaved ypn table: perm holds byte offsets (src*128 + sign*64) -> single-add addressing.
template <int DO_ASFR, int DO_RES, int DO_LIN, int WRITE_Z>
__global__ __launch_bounds__(256) void k_layer(
    const unsigned short* __restrict__ ypni,
    unsigned short* __restrict__ ysb,
    const unsigned* __restrict__ perm, const int* __restrict__ offs,
    float* __restrict__ z,
    const float* __restrict__ lnw, const float* __restrict__ lnb,
    const float* __restrict__ gw, const float* __restrict__ gb,
    const float* __restrict__ Wp, const float* __restrict__ Wn, const float* __restrict__ Ws,
    unsigned short* __restrict__ ypno) {
  __shared__ float4 wps[8][32], wns[8][32], wss[8][32], gws[8][32];
  __shared__ float zrow[8][36], xrow[8][36];
  int t = threadIdx.x;
  if (DO_LIN) {
    int k4 = t >> 5, c = t & 31;   // 256 threads = exactly 8*32 float4 per matrix
    wps[k4][c] = ((const float4*)Wp)[c * 8 + k4];
    wns[k4][c] = ((const float4*)Wn)[c * 8 + k4];
    wss[k4][c] = ((const float4*)Ws)[c * 8 + k4];
    if (DO_ASFR) gws[k4][c] = ((const float4*)gw)[c * 8 + k4];
  }
  int lane = t & 31, local = t >> 5;
  int es = lane >> 2, fs = lane & 3;  // 8 edge slots x 4 lanes (16B each)
  const char* ybase = (const char*)ypni;
  int g0 = blockIdx.x * GPB;
  int gend = (g0 + GPB < NGRP) ? g0 + GPB : NGRP;
  for (int gi = g0; gi < gend; gi++) {
    int node = gi * 8 + local;
    int beg = offs[node], end = offs[node + 1];
    float a0[8], a1[8], a2[8], a3[8];
#pragma unroll
    for (int i = 0; i < 8; i++) { a0[i] = 0.f; a1[i] = 0.f; a2[i] = 0.f; a3[i] = 0.f; }
    for (int base = beg; base < end; base += 32) {
      unsigned pe = (base + lane < end) ? perm[base + lane] : 0u;
      int rem = end - base;
      unsigned u0 = __shfl(pe, es, 32);
      unsigned u1 = __shfl(pe, es + 8, 32);
      uint4 v0 = *(const uint4*)(ybase + u0 + fs * 16);
      uint4 v1 = *(const uint4*)(ybase + u1 + fs * 16);
      if (es < rem) { ACC8(a0, v0); }
      if (es + 8 < rem) { ACC8(a1, v1); }
      if (rem > 16) {
        unsigned u2 = __shfl(pe, es + 16, 32);
        unsigned u3 = __shfl(pe, es + 24, 32);
        uint4 v2 = *(const uint4*)(ybase + u2 + fs * 16);
        uint4 v3 = *(const uint4*)(ybase + u3 + fs * 16);
        if (es + 16 < rem) { ACC8(a2, v2); }
        if (es + 24 < rem) { ACC8(a3, v3); }
      }
    }
#pragma unroll
    for (int i = 0; i < 8; i++) a0[i] += (a1[i] + a2[i]) + a3[i];
#pragma unroll
    for (int m = 4; m <= 16; m <<= 1) {
#pragma unroll
      for (int i = 0; i < 8; i++) a0[i] += __shfl_xor(a0[i], m, 32);
    }
    if (es == 0) {  // 4 lanes per node finalize 8 floats each
      uint4 sv = *((const uint4*)(ysb + (size_t)node * 32) + fs);
      float sf[8];
      sf[0] = __uint_as_float(sv.x << 16); sf[1] = __uint_as_float(sv.x & 0xffff0000u);
      sf[2] = __uint_as_float(sv.y << 16); sf[3] = __uint_as_float(sv.y & 0xffff0000u);
      sf[4] = __uint_as_float(sv.z << 16); sf[5] = __uint_as_float(sv.z & 0xffff0000u);
      sf[6] = __uint_as_float(sv.w << 16); sf[7] = __uint_as_float(sv.w & 0xffff0000u);
      float o[8];
#pragma unroll
      for (int i = 0; i < 8; i++) o[i] = elu1(a0[i] + sf[i]);
      if (DO_RES) {
        const float* rr = z + (size_t)node * 32 + fs * 8;
        F4 r0, r1;
        r0.v = *(const float4*)rr;
        r1.v = *(const float4*)(rr + 4);
#pragma unroll
        for (int i = 0; i < 4; i++) { o[i] += 0.1f * r0.f[i]; o[4 + i] += 0.1f * r1.f[i]; }
      }
#pragma unroll
      for (int i = 0; i < 8; i++) zrow[local][fs * 8 + i] = o[i];
      if (WRITE_Z) {
        float* zw = z + (size_t)node * 32 + fs * 8;
        *(float4*)zw = make_float4(o[0], o[1], o[2], o[3]);
        *(float4*)(zw + 4) = make_float4(o[4], o[5], o[6], o[7]);
      }
    }
    if (gi == g0 && DO_LIN) __syncthreads();  // weights staged (cross-wave); once per block
    if (!DO_LIN) continue;
    if (DO_ASFR) {
      float v = zrow[local][lane];
      float s = v;
#pragma unroll
      for (int m = 16; m; m >>= 1) s += __shfl_xor(s, m, 32);
      float mu = s * (1.f / 32.f);
      float d = v - mu, sq = d * d;
#pragma unroll
      for (int m = 16; m; m >>= 1) sq += __shfl_xor(sq, m, 32);
      float xn = d * rsqrtf(sq * (1.f / 32.f) + 1e-5f) * lnw[lane] + lnb[lane];
      xrow[local][lane] = xn;
      float ga = gb[lane];
#pragma unroll
      for (int k4 = 0; k4 < 8; k4++) {
        float4 xv = *((const float4*)&xrow[local][0] + k4);
        float4 w = gws[k4][lane];
        ga = fmaf(xv.w, w.w, fmaf(xv.z, w.z, fmaf(xv.y, w.y, fmaf(xv.x, w.x, ga))));
      }
      float g = 1.f / (1.f + __expf(-ga));
      float w1 = g > 0.5f ? 1.f : g;
      float w2 = g > 0.5f ? 0.f : g;
      float zn = w1 * v + __shfl_xor(w2 * v, 16, 32);
      zrow[local][lane] = zn;
    }
    float ap = 0.f, an = 0.f, asf = 0.f;
#pragma unroll
    for (int k4 = 0; k4 < 8; k4++) {
      float4 xv = *((const float4*)&zrow[local][0] + k4);
      float4 a2w = wps[k4][lane], b2 = wns[k4][lane], c2 = wss[k4][lane];
      ap  = fmaf(xv.w, a2w.w, fmaf(xv.z, a2w.z, fmaf(xv.y, a2w.y, fmaf(xv.x, a2w.x, ap))));
      an  = fmaf(xv.w, b2.w, fmaf(xv.z, b2.z, fmaf(xv.y, b2.y, fmaf(xv.x, b2.x, an))));
      asf = fmaf(xv.w, c2.w, fmaf(xv.z, c2.z, fmaf(xv.y, c2.y, fmaf(xv.x, c2.x, asf))));
    }
    size_t o64 = (size_t)node * 64 + lane;
    ypno[o64]      = __bfloat16_as_ushort(__float2bfloat16(ap));
    ypno[o64 + 32] = __bfloat16_as_ushort(__float2bfloat16(an));
    ysb[(size_t)node * 32 + lane] = __bfloat16_as_ushort(__float2bfloat16(asf));
  }
}

// ---------------- head: 128 nodes/block, 8 lanes/node x 4 nodes/thread — R9 proven ----------------
__global__ __launch_bounds__(256) void k_mlp(const float* __restrict__ z,
    const float* __restrict__ pw, const float* __restrict__ pb,
    const float* __restrict__ w1, const float* __restrict__ b1,
    const float* __restrict__ l1w, const float* __restrict__ l1b,
    const float* __restrict__ w2, const float* __restrict__ b2,
    const float* __restrict__ l2w, const float* __restrict__ l2b,
    const float* __restrict__ w3, const float* __restrict__ b3,
    float* __restrict__ outz, float* __restrict__ outp) {
  __shared__ float4 wbuf[1536];
  __shared__ float4 hbuf4[128 * 17];
  __shared__ float pb_s[64], b1_s[64], l1w_s[64], l1b_s[64], b2_s[64], l2w_s[64], l2b_s[64], w3_s[64];
  int t = threadIdx.x;
  for (int i = t; i < 512; i += 256) {
    int k = i >> 4, j4 = i & 15;
    float4 v;
    v.x = pw[(j4 * 4 + 0) * 32 + k]; v.y = pw[(j4 * 4 + 1) * 32 + k];
    v.z = pw[(j4 * 4 + 2) * 32 + k]; v.w = pw[(j4 * 4 + 3) * 32 + k];
    wbuf[i] = v;
  }
  for (int i = t; i < 1024; i += 256) {
    int k = i >> 4, j4 = i & 15;
    float4 v;
    v.x = w1[(j4 * 4 + 0) * 64 + k]; v.y = w1[(j4 * 4 + 1) * 64 + k];
    v.z = w1[(j4 * 4 + 2) * 64 + k]; v.w = w1[(j4 * 4 + 3) * 64 + k];
    wbuf[512 + i] = v;
  }
  if (t < 64) {
    pb_s[t] = pb[t]; b1_s[t] = b1[t]; l1w_s[t] = l1w[t]; l1b_s[t] = l1b[t];
    b2_s[t] = b2[t]; l2w_s[t] = l2w[t]; l2b_s[t] = l2b[t]; w3_s[t] = w3[t];
  }
  __syncthreads();
  int g = t >> 3, q = t & 7;
  int nb0 = blockIdx.x * 128 + g;
  float bb3 = b3[0];
  bool live[4];
#pragma unroll
  for (int n = 0; n < 4; n++) live[n] = (nb0 + 32 * n) < NODES;
  float acc[4][8], h[4][8];
#pragma unroll
  for (int n = 0; n < 4; n++)
    if (live[n])
      hbuf4[(n * 32 + g) * 17 + q] = ((const float4*)(z + (size_t)(nb0 + 32 * n) * 32))[q];
#pragma unroll
  for (int n = 0; n < 4; n++)
#pragma unroll
    for (int i = 0; i < 8; i++) acc[n][i] = pb_s[q * 8 + i];
#pragma unroll 2
  for (int k4 = 0; k4 < 8; k4++) {
    F4 hv[4];
#pragma unroll
    for (int n = 0; n < 4; n++) hv[n].v = hbuf4[(n * 32 + g) * 17 + k4];
#pragma unroll
    for (int c = 0; c < 4; c++) {
      float4 wa = wbuf[(k4 * 4 + c) * 16 + q * 2];
      float4 wb = wbuf[(k4 * 4 + c) * 16 + q * 2 + 1];
#pragma unroll
      for (int n = 0; n < 4; n++) {
        float hk = hv[n].f[c];
        acc[n][0] = fmaf(hk, wa.x, acc[n][0]); acc[n][1] = fmaf(hk, wa.y, acc[n][1]);
        acc[n][2] = fmaf(hk, wa.z, acc[n][2]); acc[n][3] = fmaf(hk, wa.w, acc[n][3]);
        acc[n][4] = fmaf(hk, wb.x, acc[n][4]); acc[n][5] = fmaf(hk, wb.y, acc[n][5]);
        acc[n][6] = fmaf(hk, wb.z, acc[n][6]); acc[n][7] = fmaf(hk, wb.w, acc[n][7]);
      }
    }
  }
#pragma unroll
  for (int n = 0; n < 4; n++) {
#pragma unroll
    for (int i = 0; i < 8; i++) h[n][i] = elu1(acc[n][i]);
    float4 h0 = make_float4(h[n][0], h[n][1], h[n][2], h[n][3]);
    float4 h1 = make_float4(h[n][4], h[n][5], h[n][6], h[n][7]);
    if (live[n]) {
      float4* oz = (float4*)(outz + (size_t)(nb0 + 32 * n) * 64 + q * 8);
      oz[0] = h0; oz[1] = h1;
    }
    hbuf4[(n * 32 + g) * 17 + 2 * q] = h0;
    hbuf4[(n * 32 + g) * 17 + 2 * q + 1] = h1;
  }
#pragma unroll
  for (int n = 0; n < 4; n++)
#pragma unroll
    for (int i = 0; i < 8; i++) acc[n][i] = b1_s[q * 8 + i];
#pragma unroll 2
  for (int k4 = 0; k4 < 16; k4++) {
    F4 hv[4];
#pragma unroll
    for (int n = 0; n < 4; n++) hv[n].v = hbuf4[(n * 32 + g) * 17 + k4];
#pragma unroll
    for (int c = 0; c < 4; c++) {
      float4 wa = wbuf[512 + (k4 * 4 + c) * 16 + q * 2];
      float4 wb = wbuf[512 + (k4 * 4 + c) * 16 + q * 2 + 1];
#pragma unroll
      for (int n = 0; n < 4; n++) {
        float hk = hv[n].f[c];
        acc[n][0] = fmaf(hk, wa.x, acc[n][0]); acc[n][1] = fmaf(hk, wa.y, acc[n][1]);
        acc[n][2] = fmaf(hk, wa.z, acc[n][2]); acc[n][3] = fmaf(hk, wa.w, acc[n][3]);
        acc[n][4] = fmaf(hk, wb.x, acc[n][4]); acc[n][5] = fmaf(hk, wb.y, acc[n][5]);
        acc[n][6] = fmaf(hk, wb.z, acc[n][6]); acc[n][7] = fmaf(hk, wb.w, acc[n][7]);
      }
    }
  }
  __syncthreads();
  for (int i = t; i < 1024; i += 256) {
    int k = i >> 4, j4 = i & 15;
    float4 v;
    v.x = w2[(j4 * 4 + 0) * 64 + k]; v.y = w2[(j4 * 4 + 1) * 64 + k];
    v.z = w2[(j4 * 4 + 2) * 64 + k]; v.w = w2[(j4 * 4 + 3) * 64 + k];
    wbuf[i] = v;
  }
#pragma unroll
  for (int n = 0; n < 4; n++) {
    float s = 0.f;
#pragma unroll
    for (int i = 0; i < 8; i++) s += acc[n][i];
    s += __shfl_xor(s, 1, 8); s += __shfl_xor(s, 2, 8); s += __shfl_xor(s, 4, 8);
    float mu = s * (1.f / 64.f);
    float vs = 0.f;
#pragma unroll
    for (int i = 0; i < 8; i++) { float dd = acc[n][i] - mu; vs += dd * dd; }
    vs += __shfl_xor(vs, 1, 8); vs += __shfl_xor(vs, 2, 8); vs += __shfl_xor(vs, 4, 8);
    float rs = rsqrtf(vs * (1.f / 64.f) + 1e-5f);
#pragma unroll
    for (int i = 0; i < 8; i++)
      h[n][i] = fmaxf((acc[n][i] - mu) * rs * l1w_s[q * 8 + i] + l1b_s[q * 8 + i], 0.f);
  }
  __syncthreads();
#pragma unroll
  for (int n = 0; n < 4; n++) {
    hbuf4[(n * 32 + g) * 17 + 2 * q] = make_float4(h[n][0], h[n][1], h[n][2], h[n][3]);
    hbuf4[(n * 32 + g) * 17 + 2 * q + 1] = make_float4(h[n][4], h[n][5], h[n][6], h[n][7]);
  }
#pragma unroll
  for (int n = 0; n < 4; n++)
#pragma unroll
    for (int i = 0; i < 8; i++) acc[n][i] = b2_s[q * 8 + i];
#pragma unroll 2
  for (int k4 = 0; k4 < 16; k4++) {
    F4 hv[4];
#pragma unroll
    for (int n = 0; n < 4; n++) hv[n].v = hbuf4[(n * 32 + g) * 17 + k4];
#pragma unroll
    for (int c = 0; c < 4; c++) {
      float4 wa = wbuf[(k4 * 4 + c) * 16 + q * 2];
      float4 wb = wbuf[(k4 * 4 + c) * 16 + q * 2 + 1];
#pragma unroll
      for (int n = 0; n < 4; n++) {
        float hk = hv[n].f[c];
        acc[n][0] = fmaf(hk, wa.x, acc[n][0]); acc[n][1] = fmaf(hk, wa.y, acc[n][1]);
        acc[n][2] = fmaf(hk, wa.z, acc[n][2]); acc[n][3] = fmaf(hk, wa.w, acc[n][3]);
        acc[n][4] = fmaf(hk, wb.x, acc[n][4]); acc[n][5] = fmaf(hk, wb.y, acc[n][5]);
        acc[n][6] = fmaf(hk, wb.z, acc[n][6]); acc[n][7] = fmaf(hk, wb.w, acc[n][7]);
      }
    }
  }
#pragma unroll
  for (int n = 0; n < 4; n++) {
    float s = 0.f;
#pragma unroll
    for (int i = 0; i < 8; i++) s += acc[n][i];
    s += __shfl_xor(s, 1, 8); s += __shfl_xor(s, 2, 8); s += __shfl_xor(s, 4, 8);
    float mu = s * (1.f / 64.f);
    float vs = 0.f;
#pragma unroll
    for (int i = 0; i < 8; i++) { float dd = acc[n][i] - mu; vs += dd * dd; }
    vs += __shfl_xor(vs, 1, 8); vs += __shfl_xor(vs, 2, 8); vs += __shfl_xor(vs, 4, 8);
    float rs = rsqrtf(vs * (1.f / 64.f) + 1e-5f);
    float p = 0.f;
#pragma unroll
    for (int i = 0; i < 8; i++) {
      float hv2 = fmaxf((acc[n][i] - mu) * rs * l2w_s[q * 8 + i] + l2b_s[q * 8 + i], 0.f);
      p = fmaf(hv2, w3_s[q * 8 + i], p);
    }
    p += __shfl_xor(p, 1, 8); p += __shfl_xor(p, 2, 8); p += __shfl_xor(p, 4, 8);
    if (q == 0 && live[n]) outp[nb0 + 32 * n] = 1.f / (1.f + __expf(-(p + bb3)));
  }
}

extern "C" void kernel_launch(void* const* d_in, const int* in_sizes, int n_in,
                              void* d_out, int out_size, void* d_ws, size_t ws_size,
                              hipStream_t stream) {
  const float* init_emb = (const float*)d_in[0];
  const int*   ei  = (const int*)d_in[1];
  const float* W1p = (const float*)d_in[2];
  const float* W1n = (const float*)d_in[3];
  const float* W1s = (const float*)d_in[4];
  const float* Wlp = (const float*)d_in[5];
  const float* Wln = (const float*)d_in[6];
  const float* Wls = (const float*)d_in[7];
  const float* lnw = (const float*)d_in[8];
  const float* lnb = (const float*)d_in[9];
  const float* gw  = (const float*)d_in[10];
  const float* gb  = (const float*)d_in[11];
  const float* pw  = (const float*)d_in[12];
  const float* pb  = (const float*)d_in[13];
  const float* w1  = (const float*)d_in[14];
  const float* b1  = (const float*)d_in[15];
  const float* l1w = (const float*)d_in[16];
  const float* l1b = (const float*)d_in[17];
  const float* w2  = (const float*)d_in[18];
  const float* b2  = (const float*)d_in[19];
  const float* l2w = (const float*)d_in[20];
  const float* l2b = (const float*)d_in[21];
  const float* w3  = (const float*)d_in[22];
  const float* b3  = (const float*)d_in[23];

  char* ws = (char*)d_ws;
  size_t off = 0;
  auto alloc = [&](size_t b) { void* p = ws + off; off = (off + b + 255) & ~(size_t)255; return p; };
  unsigned short* ypnA = (unsigned short*)alloc((size_t)NODES * 64 * 2);  // interleaved {pos|neg}
  unsigned short* ypnB = (unsigned short*)alloc((size_t)NODES * 64 * 2);
  unsigned short* ysb  = (unsigned short*)alloc((size_t)NODES * 32 * 2);
  float*    zbuf   = (float*)alloc((size_t)NODES * 32 * 4);
  unsigned* perm   = (unsigned*)alloc((size_t)EDGES * 4);
  int*      offs   = (int*)alloc((NODES + 1) * 4);
  int*      bucket_cnt    = (int*)alloc(NBUCK * 4);
  int*      bucket_base   = (int*)alloc(NBUCK * 4);
  int*      bucket_cursor = (int*)alloc(NBUCK * 4);
  unsigned* binned = (unsigned*)ypnA;  // 3.2MB alias (dead until k_lin64)

  // ---- CSR build ----
  hipMemsetAsync(bucket_cnt, 0, NBUCK * 4, stream);
  k_bhist<<<NBIN_BLOCKS, 256, 0, stream>>>(ei, bucket_cnt);
  k_bscan<<<1, 256, 0, stream>>>(bucket_cnt, bucket_base, bucket_cursor);
  k_bin<<<NBIN_BLOCKS, 256, 0, stream>>>(ei, bucket_cursor, binned);
  k_scatter2<<<NBUCK, 256, 0, stream>>>(binned, bucket_base, bucket_cnt, offs, perm);

  // ---- layer 1 linear (K=64) -> ypnA + ysb ----
  k_lin64<<<NODES / 8, 256, 0, stream>>>(init_emb, W1p, W1n, W1s, ypnA, ysb);

  // ---- conv layers ----
  // L0: agg + ASFR + lin(Wl[0]); no residual, no z write; A -> B
  k_layer<1, 0, 1, 0><<<LGRID, 256, 0, stream>>>(ypnA, ysb, perm, offs, zbuf,
      lnw, lnb, gw, gb, Wlp, Wln, Wls, ypnB);
  // L1: agg no residual, write z, lin Wl[1]; B -> A
  k_layer<0, 0, 1, 1><<<LGRID, 256, 0, stream>>>(ypnB, ysb, perm, offs, zbuf,
      nullptr, nullptr, nullptr, nullptr, Wlp + 1024, Wln + 1024, Wls + 1024, ypnA);
  // L2..L7: agg + residual, write z, lin Wl[2..7]
  unsigned short* yin = ypnA;
  unsigned short* yout = ypnB;
  for (int i = 1; i < 7; i++) {
    k_layer<0, 1, 1, 1><<<LGRID, 256, 0, stream>>>(yin, ysb, perm, offs, zbuf,
        nullptr, nullptr, nullptr, nullptr,
        Wlp + (i + 1) * 1024, Wln + (i + 1) * 1024, Wls + (i + 1) * 1024, yout);
    unsigned short* tp = yin; yin = yout; yout = tp;
  }
  // L8: agg + residual, write z, no lin
  k_layer<0, 1, 0, 1><<<LGRID, 256, 0, stream>>>(yin, ysb, perm, offs, zbuf,
      nullptr, nullptr, nullptr, nullptr, nullptr, nullptr, nullptr, nullptr);

  // ---- fused head ----
  float* outz = (float*)d_out;
  float* outp = outz + (size_t)NODES * 64;
  k_mlp<<<(NODES + 127) / 128, 256, 0, stream>>>(zbuf, pw, pb, w1, b1, l1w, l1b,
                                                 w2, b2, l2w, l2b, w3, b3, outz, outp);
}

// Round 15
// 344.384 us; speedup vs baseline: 1.1738x; 1.1738x over previous
//
#include <hip/hip_runtime.h>
#include <hip/hip_bf16.h>

#define NODES 50000
#define EDGES 800000
#define BSH 8
#define NBUCK 196          // ceil(50000 / 256)
#define NBIN_BLOCKS 391    // ceil(800000 / 2048)
#define NGRP 6250          // NODES / 8

__device__ __forceinline__ float elu1(float x) { return x > 0.f ? x : expm1f(x); }

union F4 { float4 v; float f[4]; };

// ---------------- bucket histogram (256-node buckets) ----------------
__global__ __launch_bounds__(256) void k_bhist(const int* __restrict__ ei, int* __restrict__ bucket_cnt) {
  __shared__ int cnt[NBUCK];
  int t = threadIdx.x;
  for (int i = t; i < NBUCK; i += 256) cnt[i] = 0;
  __syncthreads();
  int base = blockIdx.x * 2048;
#pragma unroll
  for (int i = 0; i < 8; i++) {
    int e = base + i * 256 + t;
    if (e < EDGES) atomicAdd(&cnt[ei[e * 3 + 1] >> BSH], 1);
  }
  __syncthreads();
  for (int i = t; i < NBUCK; i += 256)
    if (cnt[i]) atomicAdd(bucket_cnt + i, cnt[i]);
}

__global__ __launch_bounds__(256) void k_bscan(const int* __restrict__ bucket_cnt,
                                               int* __restrict__ bucket_base,
                                               int* __restrict__ bucket_cursor) {
  __shared__ int s[256];
  int t = threadIdx.x;
  int v = (t < NBUCK) ? bucket_cnt[t] : 0;
  s[t] = v;
  __syncthreads();
  for (int o = 1; o < 256; o <<= 1) {
    int x = (t >= o) ? s[t - o] : 0;
    __syncthreads();
    s[t] += x;
    __syncthreads();
  }
  if (t < NBUCK) { int e = s[t] - v; bucket_base[t] = e; bucket_cursor[t] = e; }
}

// pass A: bin edges by tgt-bucket; packed record: src[15:0] | sign[16] | tgtlow8[24:17]
__global__ __launch_bounds__(256) void k_bin(const int* __restrict__ ei,
                                             int* __restrict__ bucket_cursor,
                                             unsigned* __restrict__ binned) {
  __shared__ int cnt[NBUCK], basec[NBUCK];
  int t = threadIdx.x;
  for (int i = t; i < NBUCK; i += 256) cnt[i] = 0;
  __syncthreads();
  int eb = blockIdx.x * 2048;
#pragma unroll
  for (int i = 0; i < 8; i++) {
    int e = eb + i * 256 + t;
    if (e < EDGES) atomicAdd(&cnt[ei[e * 3 + 1] >> BSH], 1);
  }
  __syncthreads();
  for (int i = t; i < NBUCK; i += 256) {
    int c = cnt[i];
    basec[i] = c ? atomicAdd(bucket_cursor + i, c) : 0;
    cnt[i] = 0;
  }
  __syncthreads();
#pragma unroll
  for (int i = 0; i < 8; i++) {
    int e = eb + i * 256 + t;
    if (e < EDGES) {
      int src = ei[e * 3 + 0];
      int tgt = ei[e * 3 + 1];
      int sg  = ei[e * 3 + 2];
      unsigned val = (unsigned)src | (sg < 0 ? 0x10000u : 0u) | ((unsigned)(tgt & 255) << 17);
      int bkt = tgt >> BSH;
      int r = atomicAdd(&cnt[bkt], 1);
      binned[basec[bkt] + r] = val;
    }
  }
}

// pass B: derives offs from per-bucket histogram+scan, then scatters.
// perm entry = BYTE offset into interleaved ypn table: src*128 + sign*64.
__global__ __launch_bounds__(256) void k_scatter2(const unsigned* __restrict__ binned,
                                                  const int* __restrict__ bucket_base,
                                                  const int* __restrict__ bucket_cnt,
                                                  int* __restrict__ offs,
                                                  unsigned* __restrict__ perm) {
  __shared__ int cnt[256];
  __shared__ int s[256];
  int b = blockIdx.x, t = threadIdx.x;
  int t0 = b << BSH;
  cnt[t] = 0;
  __syncthreads();
  int n = bucket_cnt[b], bb = bucket_base[b];
  for (int i = t; i < n; i += 256) atomicAdd(&cnt[(binned[bb + i] >> 17) & 255], 1);
  __syncthreads();
  int v = cnt[t];
  s[t] = v;
  __syncthreads();
  for (int o = 1; o < 256; o <<= 1) {
    int x = (t >= o) ? s[t - o] : 0;
    __syncthreads();
    s[t] += x;
    __syncthreads();
  }
  int pos = bb + s[t] - v;
  if (t0 + t < NODES) offs[t0 + t] = pos;
  cnt[t] = pos;
  if (b == 0 && t == 0) offs[NODES] = EDGES;
  __syncthreads();
  for (int i = t; i < n; i += 256) {
    unsigned e = binned[bb + i];
    int p = atomicAdd(&cnt[(e >> 17) & 255], 1);
    perm[p] = ((e & 0xFFFFu) << 7) | ((e & 0x10000u) >> 10);  // src*128 + sign*64
  }
}

// ---------------- first linear: y = x @ {Wp,Wn,Ws}.T (out 32, K=64) -> interleaved ypn + ysb ----------------
__global__ __launch_bounds__(256) void k_lin64(const float* __restrict__ x,
    const float* __restrict__ Wp, const float* __restrict__ Wn, const float* __restrict__ Ws,
    unsigned short* __restrict__ ypn, unsigned short* __restrict__ ysb) {
  constexpr int K4 = 16;
  __shared__ float4 wp[K4][32], wn[K4][32], wsm[K4][32];
  __shared__ float4 xs[8][K4];
  for (int i = threadIdx.x; i < 32 * K4; i += 256) {
    int k4 = i >> 5, c = i & 31;
    wp[k4][c]  = ((const float4*)Wp)[c * K4 + k4];
    wn[k4][c]  = ((const float4*)Wn)[c * K4 + k4];
    wsm[k4][c] = ((const float4*)Ws)[c * K4 + k4];
  }
  int base = blockIdx.x * 8;
  for (int i = threadIdx.x; i < 8 * K4; i += 256) {
    int r = i / K4, k4 = i - r * K4;
    xs[r][k4] = ((const float4*)(x + (size_t)(base + r) * 64))[k4];
  }
  __syncthreads();
  int lane = threadIdx.x & 31, local = threadIdx.x >> 5;
  float ap = 0.f, an = 0.f, asf = 0.f;
#pragma unroll
  for (int k4 = 0; k4 < K4; k4++) {
    float4 xv = xs[local][k4];
    float4 a = wp[k4][lane], b = wn[k4][lane], c = wsm[k4][lane];
    ap  = fmaf(xv.w, a.w, fmaf(xv.z, a.z, fmaf(xv.y, a.y, fmaf(xv.x, a.x, ap))));
    an  = fmaf(xv.w, b.w, fmaf(xv.z, b.z, fmaf(xv.y, b.y, fmaf(xv.x, b.x, an))));
    asf = fmaf(xv.w, c.w, fmaf(xv.z, c.z, fmaf(xv.y, c.y, fmaf(xv.x, c.x, asf))));
  }
  int node = base + local;
  size_t o64 = (size_t)node * 64 + lane;
  ypn[o64]      = __bfloat16_as_ushort(__float2bfloat16(ap));
  ypn[o64 + 32] = __bfloat16_as_ushort(__float2bfloat16(an));
  ysb[(size_t)node * 32 + lane] = __bfloat16_as_ushort(__float2bfloat16(asf));
}

#define ACC8(A, V)                                   \
  A[0] += __uint_as_float((V).x << 16);              \
  A[1] += __uint_as_float((V).x & 0xffff0000u);      \
  A[2] += __uint_as_float((V).y << 16);              \
  A[3] += __uint_as_float((V).y & 0xffff0000u);      \
  A[4] += __uint_as_float((V).z << 16);              \
  A[5] += __uint_as_float((V).z & 0xffff0000u);      \
  A[6] += __uint_as_float((V).w << 16);              \
  A[7] += __uint_as_float((V).w & 0xffff0000u);

// ---------------- fused layer: gather + ELU (+res) (+ASFR) (+lin) ----------------
// R13 structure (one node-group per block, grid = NGRP) + byte-offset interleaved gather.
template <int DO_ASFR, int DO_RES, int DO_LIN, int WRITE_Z>
__global__ __launch_bounds__(256) void k_layer(
    const unsigned short* __restrict__ ypni,
    unsigned short* __restrict__ ysb,
    const unsigned* __restrict__ perm, const int* __restrict__ offs,
    float* __restrict__ z,
    const float* __restrict__ lnw, const float* __restrict__ lnb,
    const float* __restrict__ gw, const float* __restrict__ gb,
    const float* __restrict__ Wp, const float* __restrict__ Wn, const float* __restrict__ Ws,
    unsigned short* __restrict__ ypno) {
  __shared__ float4 wps[8][32], wns[8][32], wss[8][32], gws[8][32];
  __shared__ float zrow[8][36], xrow[8][36];
  int t = threadIdx.x;
  if (DO_LIN) {
    int k4 = t >> 5, c = t & 31;   // 256 threads = exactly 8*32 float4 per matrix
    wps[k4][c] = ((const float4*)Wp)[c * 8 + k4];
    wns[k4][c] = ((const float4*)Wn)[c * 8 + k4];
    wss[k4][c] = ((const float4*)Ws)[c * 8 + k4];
    if (DO_ASFR) gws[k4][c] = ((const float4*)gw)[c * 8 + k4];
  }
  int lane = t & 31, local = t >> 5;
  int node = blockIdx.x * 8 + local;
  int es = lane >> 2, fs = lane & 3;  // 8 edge slots x 4 lanes (16B each)
  const char* ybase = (const char*)ypni;
  int beg = offs[node], end = offs[node + 1];
  float a0[8], a1[8], a2[8], a3[8];
#pragma unroll
  for (int i = 0; i < 8; i++) { a0[i] = 0.f; a1[i] = 0.f; a2[i] = 0.f; a3[i] = 0.f; }
  for (int base = beg; base < end; base += 32) {
    unsigned pe = (base + lane < end) ? perm[base + lane] : 0u;
    int rem = end - base;
    unsigned u0 = __shfl(pe, es, 32);
    unsigned u1 = __shfl(pe, es + 8, 32);
    uint4 v0 = *(const uint4*)(ybase + u0 + fs * 16);
    uint4 v1 = *(const uint4*)(ybase + u1 + fs * 16);
    if (es < rem) { ACC8(a0, v0); }
    if (es + 8 < rem) { ACC8(a1, v1); }
    if (rem > 16) {
      unsigned u2 = __shfl(pe, es + 16, 32);
      unsigned u3 = __shfl(pe, es + 24, 32);
      uint4 v2 = *(const uint4*)(ybase + u2 + fs * 16);
      uint4 v3 = *(const uint4*)(ybase + u3 + fs * 16);
      if (es + 16 < rem) { ACC8(a2, v2); }
      if (es + 24 < rem) { ACC8(a3, v3); }
    }
  }
#pragma unroll
  for (int i = 0; i < 8; i++) a0[i] += (a1[i] + a2[i]) + a3[i];
#pragma unroll
  for (int m = 4; m <= 16; m <<= 1) {
#pragma unroll
    for (int i = 0; i < 8; i++) a0[i] += __shfl_xor(a0[i], m, 32);
  }
  if (es == 0) {  // 4 lanes per node finalize 8 floats each
    uint4 sv = *((const uint4*)(ysb + (size_t)node * 32) + fs);
    float sf[8];
    sf[0] = __uint_as_float(sv.x << 16); sf[1] = __uint_as_float(sv.x & 0xffff0000u);
    sf[2] = __uint_as_float(sv.y << 16); sf[3] = __uint_as_float(sv.y & 0xffff0000u);
    sf[4] = __uint_as_float(sv.z << 16); sf[5] = __uint_as_float(sv.z & 0xffff0000u);
    sf[6] = __uint_as_float(sv.w << 16); sf[7] = __uint_as_float(sv.w & 0xffff0000u);
    float o[8];
#pragma unroll
    for (int i = 0; i < 8; i++) o[i] = elu1(a0[i] + sf[i]);
    if (DO_RES) {
      const float* rr = z + (size_t)node * 32 + fs * 8;
      F4 r0, r1;
      r0.v = *(const float4*)rr;
      r1.v = *(const float4*)(rr + 4);
#pragma unroll
      for (int i = 0; i < 4; i++) { o[i] += 0.1f * r0.f[i]; o[4 + i] += 0.1f * r1.f[i]; }
    }
#pragma unroll
    for (int i = 0; i < 8; i++) zrow[local][fs * 8 + i] = o[i];
    if (WRITE_Z) {
      float* zw = z + (size_t)node * 32 + fs * 8;
      *(float4*)zw = make_float4(o[0], o[1], o[2], o[3]);
      *(float4*)(zw + 4) = make_float4(o[4], o[5], o[6], o[7]);
    }
  }
  __syncthreads();  // weights staged (cross-wave); zrow (in-wave) ready
  if (!DO_LIN) return;
  if (DO_ASFR) {
    float v = zrow[local][lane];
    float s = v;
#pragma unroll
    for (int m = 16; m; m >>= 1) s += __shfl_xor(s, m, 32);
    float mu = s * (1.f / 32.f);
    float d = v - mu, sq = d * d;
#pragma unroll
    for (int m = 16; m; m >>= 1) sq += __shfl_xor(sq, m, 32);
    float xn = d * rsqrtf(sq * (1.f / 32.f) + 1e-5f) * lnw[lane] + lnb[lane];
    xrow[local][lane] = xn;
    float ga = gb[lane];
#pragma unroll
    for (int k4 = 0; k4 < 8; k4++) {
      float4 xv = *((const float4*)&xrow[local][0] + k4);
      float4 w = gws[k4][lane];
      ga = fmaf(xv.w, w.w, fmaf(xv.z, w.z, fmaf(xv.y, w.y, fmaf(xv.x, w.x, ga))));
    }
    float g = 1.f / (1.f + __expf(-ga));
    float w1 = g > 0.5f ? 1.f : g;
    float w2 = g > 0.5f ? 0.f : g;
    float zn = w1 * v + __shfl_xor(w2 * v, 16, 32);
    zrow[local][lane] = zn;
  }
  float ap = 0.f, an = 0.f, asf = 0.f;
#pragma unroll
  for (int k4 = 0; k4 < 8; k4++) {
    float4 xv = *((const float4*)&zrow[local][0] + k4);
    float4 a2w = wps[k4][lane], b2 = wns[k4][lane], c2 = wss[k4][lane];
    ap  = fmaf(xv.w, a2w.w, fmaf(xv.z, a2w.z, fmaf(xv.y, a2w.y, fmaf(xv.x, a2w.x, ap))));
    an  = fmaf(xv.w, b2.w, fmaf(xv.z, b2.z, fmaf(xv.y, b2.y, fmaf(xv.x, b2.x, an))));
    asf = fmaf(xv.w, c2.w, fmaf(xv.z, c2.z, fmaf(xv.y, c2.y, fmaf(xv.x, c2.x, asf))));
  }
  size_t o64 = (size_t)node * 64 + lane;
  ypno[o64]      = __bfloat16_as_ushort(__float2bfloat16(ap));
  ypno[o64 + 32] = __bfloat16_as_ushort(__float2bfloat16(an));
  ysb[(size_t)node * 32 + lane] = __bfloat16_as_ushort(__float2bfloat16(asf));
}

// ---------------- head: 128 nodes/block, 8 lanes/node x 4 nodes/thread — R9 proven ----------------
__global__ __launch_bounds__(256) void k_mlp(const float* __restrict__ z,
    const float* __restrict__ pw, const float* __restrict__ pb,
    const float* __restrict__ w1, const float* __restrict__ b1,
    const float* __restrict__ l1w, const float* __restrict__ l1b,
    const float* __restrict__ w2, const float* __restrict__ b2,
    const float* __restrict__ l2w, const float* __restrict__ l2b,
    const float* __restrict__ w3, const float* __restrict__ b3,
    float* __restrict__ outz, float* __restrict__ outp) {
  __shared__ float4 wbuf[1536];
  __shared__ float4 hbuf4[128 * 17];
  __shared__ float pb_s[64], b1_s[64], l1w_s[64], l1b_s[64], b2_s[64], l2w_s[64], l2b_s[64], w3_s[64];
  int t = threadIdx.x;
  for (int i = t; i < 512; i += 256) {
    int k = i >> 4, j4 = i & 15;
    float4 v;
    v.x = pw[(j4 * 4 + 0) * 32 + k]; v.y = pw[(j4 * 4 + 1) * 32 + k];
    v.z = pw[(j4 * 4 + 2) * 32 + k]; v.w = pw[(j4 * 4 + 3) * 32 + k];
    wbuf[i] = v;
  }
  for (int i = t; i < 1024; i += 256) {
    int k = i >> 4, j4 = i & 15;
    float4 v;
    v.x = w1[(j4 * 4 + 0) * 64 + k]; v.y = w1[(j4 * 4 + 1) * 64 + k];
    v.z = w1[(j4 * 4 + 2) * 64 + k]; v.w = w1[(j4 * 4 + 3) * 64 + k];
    wbuf[512 + i] = v;
  }
  if (t < 64) {
    pb_s[t] = pb[t]; b1_s[t] = b1[t]; l1w_s[t] = l1w[t]; l1b_s[t] = l1b[t];
    b2_s[t] = b2[t]; l2w_s[t] = l2w[t]; l2b_s[t] = l2b[t]; w3_s[t] = w3[t];
  }
  __syncthreads();
  int g = t >> 3, q = t & 7;
  int nb0 = blockIdx.x * 128 + g;
  float bb3 = b3[0];
  bool live[4];
#pragma unroll
  for (int n = 0; n < 4; n++) live[n] = (nb0 + 32 * n) < NODES;
  float acc[4][8], h[4][8];
#pragma unroll
  for (int n = 0; n < 4; n++)
    if (live[n])
      hbuf4[(n * 32 + g) * 17 + q] = ((const float4*)(z + (size_t)(nb0 + 32 * n) * 32))[q];
#pragma unroll
  for (int n = 0; n < 4; n++)
#pragma unroll
    for (int i = 0; i < 8; i++) acc[n][i] = pb_s[q * 8 + i];
#pragma unroll 2
  for (int k4 = 0; k4 < 8; k4++) {
    F4 hv[4];
#pragma unroll
    for (int n = 0; n < 4; n++) hv[n].v = hbuf4[(n * 32 + g) * 17 + k4];
#pragma unroll
    for (int c = 0; c < 4; c++) {
      float4 wa = wbuf[(k4 * 4 + c) * 16 + q * 2];
      float4 wb = wbuf[(k4 * 4 + c) * 16 + q * 2 + 1];
#pragma unroll
      for (int n = 0; n < 4; n++) {
        float hk = hv[n].f[c];
        acc[n][0] = fmaf(hk, wa.x, acc[n][0]); acc[n][1] = fmaf(hk, wa.y, acc[n][1]);
        acc[n][2] = fmaf(hk, wa.z, acc[n][2]); acc[n][3] = fmaf(hk, wa.w, acc[n][3]);
        acc[n][4] = fmaf(hk, wb.x, acc[n][4]); acc[n][5] = fmaf(hk, wb.y, acc[n][5]);
        acc[n][6] = fmaf(hk, wb.z, acc[n][6]); acc[n][7] = fmaf(hk, wb.w, acc[n][7]);
      }
    }
  }
#pragma unroll
  for (int n = 0; n < 4; n++) {
#pragma unroll
    for (int i = 0; i < 8; i++) h[n][i] = elu1(acc[n][i]);
    float4 h0 = make_float4(h[n][0], h[n][1], h[n][2], h[n][3]);
    float4 h1 = make_float4(h[n][4], h[n][5], h[n][6], h[n][7]);
    if (live[n]) {
      float4* oz = (float4*)(outz + (size_t)(nb0 + 32 * n) * 64 + q * 8);
      oz[0] = h0; oz[1] = h1;
    }
    hbuf4[(n * 32 + g) * 17 + 2 * q] = h0;
    hbuf4[(n * 32 + g) * 17 + 2 * q + 1] = h1;
  }
#pragma unroll
  for (int n = 0; n < 4; n++)
#pragma unroll
    for (int i = 0; i < 8; i++) acc[n][i] = b1_s[q * 8 + i];
#pragma unroll 2
  for (int k4 = 0; k4 < 16; k4++) {
    F4 hv[4];
#pragma unroll
    for (int n = 0; n < 4; n++) hv[n].v = hbuf4[(n * 32 + g) * 17 + k4];
#pragma unroll
    for (int c = 0; c < 4; c++) {
      float4 wa = wbuf[512 + (k4 * 4 + c) * 16 + q * 2];
      float4 wb = wbuf[512 + (k4 * 4 + c) * 16 + q * 2 + 1];
#pragma unroll
      for (int n = 0; n < 4; n++) {
        float hk = hv[n].f[c];
        acc[n][0] = fmaf(hk, wa.x, acc[n][0]); acc[n][1] = fmaf(hk, wa.y, acc[n][1]);
        acc[n][2] = fmaf(hk, wa.z, acc[n][2]); acc[n][3] = fmaf(hk, wa.w, acc[n][3]);
        acc[n][4] = fmaf(hk, wb.x, acc[n][4]); acc[n][5] = fmaf(hk, wb.y, acc[n][5]);
        acc[n][6] = fmaf(hk, wb.z, acc[n][6]); acc[n][7] = fmaf(hk, wb.w, acc[n][7]);
      }
    }
  }
  __syncthreads();
  for (int i = t; i < 1024; i += 256) {
    int k = i >> 4, j4 = i & 15;
    float4 v;
    v.x = w2[(j4 * 4 + 0) * 64 + k]; v.y = w2[(j4 * 4 + 1) * 64 + k];
    v.z = w2[(j4 * 4 + 2) * 64 + k]; v.w = w2[(j4 * 4 + 3) * 64 + k];
    wbuf[i] = v;
  }
#pragma unroll
  for (int n = 0; n < 4; n++) {
    float s = 0.f;
#pragma unroll
    for (int i = 0; i < 8; i++) s += acc[n][i];
    s += __shfl_xor(s, 1, 8); s += __shfl_xor(s, 2, 8); s += __shfl_xor(s, 4, 8);
    float mu = s * (1.f / 64.f);
    float vs = 0.f;
#pragma unroll
    for (int i = 0; i < 8; i++) { float dd = acc[n][i] - mu; vs += dd * dd; }
    vs += __shfl_xor(vs, 1, 8); vs += __shfl_xor(vs, 2, 8); vs += __shfl_xor(vs, 4, 8);
    float rs = rsqrtf(vs * (1.f / 64.f) + 1e-5f);
#pragma unroll
    for (int i = 0; i < 8; i++)
      h[n][i] = fmaxf((acc[n][i] - mu) * rs * l1w_s[q * 8 + i] + l1b_s[q * 8 + i], 0.f);
  }
  __syncthreads();
#pragma unroll
  for (int n = 0; n < 4; n++) {
    hbuf4[(n * 32 + g) * 17 + 2 * q] = make_float4(h[n][0], h[n][1], h[n][2], h[n][3]);
    hbuf4[(n * 32 + g) * 17 + 2 * q + 1] = make_float4(h[n][4], h[n][5], h[n][6], h[n][7]);
  }
#pragma unroll
  for (int n = 0; n < 4; n++)
#pragma unroll
    for (int i = 0; i < 8; i++) acc[n][i] = b2_s[q * 8 + i];
#pragma unroll 2
  for (int k4 = 0; k4 < 16; k4++) {
    F4 hv[4];
#pragma unroll
    for (int n = 0; n < 4; n++) hv[n].v = hbuf4[(n * 32 + g) * 17 + k4];
#pragma unroll
    for (int c = 0; c < 4; c++) {
      float4 wa = wbuf[(k4 * 4 + c) * 16 + q * 2];
      float4 wb = wbuf[(k4 * 4 + c) * 16 + q * 2 + 1];
#pragma unroll
      for (int n = 0; n < 4; n++) {
        float hk = hv[n].f[c];
        acc[n][0] = fmaf(hk, wa.x, acc[n][0]); acc[n][1] = fmaf(hk, wa.y, acc[n][1]);
        acc[n][2] = fmaf(hk, wa.z, acc[n][2]); acc[n][3] = fmaf(hk, wa.w, acc[n][3]);
        acc[n][4] = fmaf(hk, wb.x, acc[n][4]); acc[n][5] = fmaf(hk, wb.y, acc[n][5]);
        acc[n][6] = fmaf(hk, wb.z, acc[n][6]); acc[n][7] = fmaf(hk, wb.w, acc[n][7]);
      }
    }
  }
#pragma unroll
  for (int n = 0; n < 4; n++) {
    float s = 0.f;
#pragma unroll
    for (int i = 0; i < 8; i++) s += acc[n][i];
    s += __shfl_xor(s, 1, 8); s += __shfl_xor(s, 2, 8); s += __shfl_xor(s, 4, 8);
    float mu = s * (1.f / 64.f);
    float vs = 0.f;
#pragma unroll
    for (int i = 0; i < 8; i++) { float dd = acc[n][i] - mu; vs += dd * dd; }
    vs += __shfl_xor(vs, 1, 8); vs += __shfl_xor(vs, 2, 8); vs += __shfl_xor(vs, 4, 8);
    float rs = rsqrtf(vs * (1.f / 64.f) + 1e-5f);
    float p = 0.f;
#pragma unroll
    for (int i = 0; i < 8; i++) {
      float hv2 = fmaxf((acc[n][i] - mu) * rs * l2w_s[q * 8 + i] + l2b_s[q * 8 + i], 0.f);
      p = fmaf(hv2, w3_s[q * 8 + i], p);
    }
    p += __shfl_xor(p, 1, 8); p += __shfl_xor(p, 2, 8); p += __shfl_xor(p, 4, 8);
    if (q == 0 && live[n]) outp[nb0 + 32 * n] = 1.f / (1.f + __expf(-(p + bb3)));
  }
}

extern "C" void kernel_launch(void* const* d_in, const int* in_sizes, int n_in,
                              void* d_out, int out_size, void* d_ws, size_t ws_size,
                              hipStream_t stream) {
  const float* init_emb = (const float*)d_in[0];
  const int*   ei  = (const int*)d_in[1];
  const float* W1p = (const float*)d_in[2];
  const float* W1n = (const float*)d_in[3];
  const float* W1s = (const float*)d_in[4];
  const float* Wlp = (const float*)d_in[5];
  const float* Wln = (const float*)d_in[6];
  const float* Wls = (const float*)d_in[7];
  const float* lnw = (const float*)d_in[8];
  const float* lnb = (const float*)d_in[9];
  const float* gw  = (const float*)d_in[10];
  const float* gb  = (const float*)d_in[11];
  const float* pw  = (const float*)d_in[12];
  const float* pb  = (const float*)d_in[13];
  const float* w1  = (const float*)d_in[14];
  const float* b1  = (const float*)d_in[15];
  const float* l1w = (const float*)d_in[16];
  const float* l1b = (const float*)d_in[17];
  const float* w2  = (const float*)d_in[18];
  const float* b2  = (const float*)d_in[19];
  const float* l2w = (const float*)d_in[20];
  const float* l2b = (const float*)d_in[21];
  const float* w3  = (const float*)d_in[22];
  const float* b3  = (const float*)d_in[23];

  char* ws = (char*)d_ws;
  size_t off = 0;
  auto alloc = [&](size_t b) { void* p = ws + off; off = (off + b + 255) & ~(size_t)255; return p; };
  unsigned short* ypnA = (unsigned short*)alloc((size_t)NODES * 64 * 2);  // interleaved {pos|neg}
  unsigned short* ypnB = (unsigned short*)alloc((size_t)NODES * 64 * 2);
  unsigned short* ysb  = (unsigned short*)alloc((size_t)NODES * 32 * 2);
  float*    zbuf   = (float*)alloc((size_t)NODES * 32 * 4);
  unsigned* perm   = (unsigned*)alloc((size_t)EDGES * 4);
  int*      offs   = (int*)alloc((NODES + 1) * 4);
  int*      bucket_cnt    = (int*)alloc(NBUCK * 4);
  int*      bucket_base   = (int*)alloc(NBUCK * 4);
  int*      bucket_cursor = (int*)alloc(NBUCK * 4);
  unsigned* binned = (unsigned*)ypnA;  // 3.2MB alias (dead until k_lin64)

  // ---- CSR build ----
  hipMemsetAsync(bucket_cnt, 0, NBUCK * 4, stream);
  k_bhist<<<NBIN_BLOCKS, 256, 0, stream>>>(ei, bucket_cnt);
  k_bscan<<<1, 256, 0, stream>>>(bucket_cnt, bucket_base, bucket_cursor);
  k_bin<<<NBIN_BLOCKS, 256, 0, stream>>>(ei, bucket_cursor, binned);
  k_scatter2<<<NBUCK, 256, 0, stream>>>(binned, bucket_base, bucket_cnt, offs, perm);

  // ---- layer 1 linear (K=64) -> ypnA + ysb ----
  k_lin64<<<NODES / 8, 256, 0, stream>>>(init_emb, W1p, W1n, W1s, ypnA, ysb);

  // ---- conv layers (one node-group per block) ----
  // L0: agg + ASFR + lin(Wl[0]); no residual, no z write; A -> B
  k_layer<1, 0, 1, 0><<<NGRP, 256, 0, stream>>>(ypnA, ysb, perm, offs, zbuf,
      lnw, lnb, gw, gb, Wlp, Wln, Wls, ypnB);
  // L1: agg no residual, write z, lin Wl[1]; B -> A
  k_layer<0, 0, 1, 1><<<NGRP, 256, 0, stream>>>(ypnB, ysb, perm, offs, zbuf,
      nullptr, nullptr, nullptr, nullptr, Wlp + 1024, Wln + 1024, Wls + 1024, ypnA);
  // L2..L7: agg + residual, write z, lin Wl[2..7]
  unsigned short* yin = ypnA;
  unsigned short* yout = ypnB;
  for (int i = 1; i < 7; i++) {
    k_layer<0, 1, 1, 1><<<NGRP, 256, 0, stream>>>(yin, ysb, perm, offs, zbuf,
        nullptr, nullptr, nullptr, nullptr,
        Wlp + (i + 1) * 1024, Wln + (i + 1) * 1024, Wls + (i + 1) * 1024, yout);
    unsigned short* tp = yin; yin = yout; yout = tp;
  }
  // L8: agg + residual, write z, no lin
  k_layer<0, 1, 0, 1><<<NGRP, 256, 0, stream>>>(yin, ysb, perm, offs, zbuf,
      nullptr, nullptr, nullptr, nullptr, nullptr, nullptr, nullptr, nullptr);

  // ---- fused head ----
  float* outz = (float*)d_out;
  float* outp = outz + (size_t)NODES * 64;
  k_mlp<<<(NODES + 127) / 128, 256, 0, stream>>>(zbuf, pw, pb, w1, b1, l1w, l1b,
                                                 w2, b2, l2w, l2b, w3, b3, outz, outp);
}